// Round 12
// baseline (196.630 us; speedup 1.0000x reference)
//
#include <hip/hip_runtime.h>
#include <hip/hip_bf16.h>
#include <math.h>

// Problem constants
#define NB    4
#define NPTS  1024
#define DD    256
#define HWW   4096
#define NHEAD 8
#define DHD   32
#define VTROW 4128   // padded V^T row length in shorts (4096 + 32)

typedef short s8v  __attribute__((ext_vector_type(8)));   // 8 x bf16 bits
typedef float f4v  __attribute__((ext_vector_type(4)));
typedef float f4s  __attribute__((ext_vector_type(4)));
typedef unsigned int u2v __attribute__((ext_vector_type(2)));
typedef unsigned int u4v __attribute__((ext_vector_type(4)));

#define MFMA_BF16 __builtin_amdgcn_mfma_f32_16x16x32_bf16

// -log(10000)/256
#define PE_FACT (-9.210340371976184f / 256.0f)
// log2(e)/sqrt(32) -- folded into Q so S-MFMA output is the exp2 argument
#define QSCALE 0.2550348637f

// pack two fp32 into one dword of bf16s (truncation): lo16=bf16(lo), hi16=bf16(hi)
__device__ __forceinline__ unsigned packbf(float hi, float lo) {
    return __builtin_amdgcn_perm(__float_as_uint(hi), __float_as_uint(lo), 0x07060302u);
}
// RNE pack
__device__ __forceinline__ unsigned pack2rne(float lo, float hi) {
    __hip_bfloat16 a = __float2bfloat16(lo), b = __float2bfloat16(hi);
    return (unsigned)*(unsigned short*)&a | ((unsigned)*(unsigned short*)&b << 16);
}

// ---------------------------------------------------------------------------
// K1 (fused prep), vectorized (unchanged from R11)
// ---------------------------------------------------------------------------
__global__ __launch_bounds__(256) void prep(const float* __restrict__ lf,
                                            const float* __restrict__ gfeat,
                                            const float* __restrict__ wq,
                                            const float* __restrict__ wk,
                                            const float* __restrict__ wv,
                                            const float* __restrict__ wo,
                                            __hip_bfloat16* __restrict__ lf_pe_b,
                                            __hip_bfloat16* __restrict__ gf_pe_b,
                                            __hip_bfloat16* __restrict__ W4) {
    __shared__ float tile[32][33];
    int b = blockIdx.x, tid = threadIdx.x;
    if (b < 1024) {
        int idx4 = (b * 256 + tid) * 4;
        f4s f = *(const f4s*)(lf + idx4);
        int c = idx4 & 255;
        int p = (idx4 >> 8) & 1023;
        float x = (float)(p & 31) * (1.0f / 31.0f);
        float y = (float)(p >> 5) * (1.0f / 31.0f);
        float div0 = __expf((float)c * PE_FACT);
        float div2 = __expf((float)(c + 2) * PE_FACT);
        float e0 = f.x + __sinf(x * div0);
        float e1 = f.y + __cosf(y * div0);
        float e2 = f.z + __sinf(x * div2);
        float e3 = f.w + __cosf(y * div2);
        u2v o2 = { pack2rne(e0, e1), pack2rne(e2, e3) };
        *(u2v*)((unsigned*)lf_pe_b + (idx4 >> 1)) = o2;
    } else if (b < 5120) {
        int t = b - 1024;
        int n = t >> 10, r = t & 1023;
        int p0 = (r >> 3) * 32, c0 = (r & 7) * 32;
        int tx = tid & 31, ty = tid >> 5;
#pragma unroll
        for (int i = 0; i < 4; ++i)
            tile[ty + 8 * i][tx] = gfeat[((size_t)n * DD + (c0 + ty + 8 * i)) * HWW + p0 + tx];
        __syncthreads();
#pragma unroll
        for (int i = 0; i < 4; ++i) {
            int p = p0 + ty + 8 * i, c = c0 + tx;
            float div = __expf((float)(c & ~1) * PE_FACT);
            float pe = (c & 1) ? __cosf((float)(p >> 6) * (1.0f / 63.0f) * div)
                               : __sinf((float)(p & 63) * (1.0f / 63.0f) * div);
            gf_pe_b[((size_t)n * HWW + p) * DD + c] = __float2bfloat16(tile[tx][ty + 8 * i] + pe);
        }
    } else {
        int idx4 = ((b - 5120) * 256 + tid) * 4;
        int m = idx4 >> 16, r = idx4 & 65535;
        const float* src = (m == 0) ? wq : (m == 1) ? wk : (m == 2) ? wv : wo;
        f4s f = *(const f4s*)(src + r);
        u2v o2 = { pack2rne(f.x, f.y), pack2rne(f.z, f.w) };
        *(u2v*)((unsigned*)W4 + (idx4 >> 1)) = o2;
    }
}

// ---------------------------------------------------------------------------
// K2: W-STATIONARY fused Q/K/V GEMM (unchanged from R11)
// ---------------------------------------------------------------------------
__global__ __launch_bounds__(256, 2) void gemmQKV(const __hip_bfloat16* __restrict__ Aq,
                                                  const __hip_bfloat16* __restrict__ Akv,
                                                  const __hip_bfloat16* __restrict__ W4,
                                                  const float* __restrict__ bq,
                                                  const float* __restrict__ bk,
                                                  const float* __restrict__ bv,
                                                  __hip_bfloat16* __restrict__ Qb,
                                                  __hip_bfloat16* __restrict__ Kb,
                                                  __hip_bfloat16* __restrict__ Vtb) {
    __shared__ __align__(16) unsigned shbuf[2304];
    int tid = threadIdx.x;
    int wave = tid >> 6, lane = tid & 63;
    int quad = lane >> 4, c16 = lane & 15;
    int b = blockIdx.x;

    int typ, c0, mgrp, mstride;
    const short* Ap;
    const short* Wp;
    const float* bias;
    if (b < 128) {               // Q
        typ = 0; c0 = (b >> 5) * 64; mgrp = b & 31; mstride = 2048;
        Ap = (const short*)Aq; Wp = (const short*)W4; bias = bq;
    } else {                     // K or V
        int bb = b - 128;
        int combo = bb >> 7;
        mgrp = bb & 127; mstride = 8192;
        int mat = combo & 1;
        typ = 1 + mat;
        c0 = (combo >> 1) * 64;
        Ap = (const short*)Akv;
        Wp = (const short*)W4 + (1 + mat) * DD * DD;
        bias = mat ? bv : bk;
    }

    s8v w[8][4];
    const short* wp0 = Wp + (c0 + c16) * DD + quad * 8;
#pragma unroll
    for (int ks = 0; ks < 8; ++ks)
#pragma unroll
        for (int t = 0; t < 4; ++t)
            w[ks][t] = *(const s8v*)(wp0 + t * 16 * DD + ks * 32);
    float bvv[4];
#pragma unroll
    for (int t = 0; t < 4; ++t) bvv[t] = bias[c0 + t * 16 + c16];

    int mbase0 = mgrp * 64;
    int mbase1 = mbase0 + mstride;
    const short* ap0 = Ap + (mbase0 + wave * 16 + c16) * DD + quad * 8;
    const short* ap1 = Ap + (mbase1 + wave * 16 + c16) * DD + quad * 8;
    s8v a0[8], a1[8];
#pragma unroll
    for (int ks = 0; ks < 8; ++ks) a0[ks] = *(const s8v*)(ap0 + ks * 32);
#pragma unroll
    for (int ks = 0; ks < 8; ++ks) a1[ks] = *(const s8v*)(ap1 + ks * 32);

#pragma unroll
    for (int it = 0; it < 2; ++it) {
        int mbase = it ? mbase1 : mbase0;
        f4v acc[4];
#pragma unroll
        for (int t = 0; t < 4; ++t) acc[t] = (f4v){0.f, 0.f, 0.f, 0.f};
#pragma unroll
        for (int ks = 0; ks < 8; ++ks) {
            s8v a = it ? a1[ks] : a0[ks];
#pragma unroll
            for (int t = 0; t < 4; ++t)
                acc[t] = MFMA_BF16(a, w[ks][t], acc[t], 0, 0, 0);
        }

        if (typ != 2) {          // Q / K: transpose bounce, coalesced store
            short* kt = (short*)shbuf;           // [64][72]
            __syncthreads();
#pragma unroll
            for (int t = 0; t < 4; ++t) {
#pragma unroll
                for (int r = 0; r < 4; ++r) {
                    float v = acc[t][r] + bvv[t];
                    if (typ == 0) v *= QSCALE;
                    __hip_bfloat16 hv = __float2bfloat16(v);
                    kt[(wave * 16 + quad * 4 + r) * 72 + t * 16 + c16] = *(short*)&hv;
                }
            }
            __syncthreads();
            int pl  = tid >> 2;
            int seg = tid & 3;
            const short* src = kt + pl * 72 + seg * 16;
            u4v w0 = *(const u4v*)(src);
            u4v w1 = *(const u4v*)(src + 8);
            int h   = (c0 >> 5) + (seg >> 1);
            int dh0 = (seg & 1) * 16;
            short* dst;
            if (typ == 0) {
                int row = mbase + pl;
                int n = row >> 10, p = row & 1023;
                dst = (short*)Qb + (((size_t)(n * NHEAD + h) << 10) + p) * DHD + dh0;
            } else {
                int n = mbase >> 12, p = (mbase & 4095) + pl;
                dst = (short*)Kb + (((size_t)(n * NHEAD + h) << 12) + p) * DHD + dh0;
            }
            *(u4v*)(dst)     = w0;
            *(u4v*)(dst + 8) = w1;
        } else {                 // V: sigma-permuted transpose bounce
            unsigned (*stv)[36] = (unsigned (*)[36])shbuf;
            __syncthreads();
#pragma unroll
            for (int t = 0; t < 4; ++t) {
#pragma unroll
                for (int rp = 0; rp < 2; ++rp) {
                    __hip_bfloat16 lo = __float2bfloat16(acc[t][2 * rp] + bvv[t]);
                    __hip_bfloat16 hi = __float2bfloat16(acc[t][2 * rp + 1] + bvv[t]);
                    unsigned dw = (unsigned)*(unsigned short*)&lo |
                                  ((unsigned)*(unsigned short*)&hi << 16);
                    stv[t * 16 + c16][wave * 8 + quad * 2 + rp] = dw;
                }
            }
            __syncthreads();
            int col = tid >> 2;
            int kd  = (tid & 3) * 8;
            int grp = kd & 16;
            int ob  = kd & 15;
            unsigned vals[8];
#pragma unroll
            for (int i = 0; i < 8; ++i) {
                int o = ob + i;
                int idw = ((o >> 2) << 1) | (o & 1) | ((o & 2) << 2);
                vals[i] = stv[col][grp + idw];
            }
            int nblk = mbase >> 12;
            int kb   = mbase & 4095;
            int gh = (c0 + col) >> 5, gdh = (c0 + col) & 31;
            short* vp = (short*)Vtb + ((size_t)(nblk * NHEAD + gh) * DHD + gdh) * VTROW + kb + kd * 2;
            *(u4v*)(vp)     = (u4v){vals[0], vals[1], vals[2], vals[3]};
            *(u4v*)(vp + 8) = (u4v){vals[4], vals[5], vals[6], vals[7]};
        }
    }
}

// ---------------------------------------------------------------------------
// K3: FUSED attention + combine + output GEMM. One block = 16 q-rows x ALL
//   8 heads x ALL 4096 keys (4 waves x 2 heads each) -- no cross-block
//   dependency, so the softmax normalize, lf_pe residual, and AL @ Wo^T + bo
//   all happen in-block. Opart/lpart eliminated.
//   grid 256 (1 block/CU), XCD-swizzled: n pinned to XCDs {n, n+4} so the
//   64 blocks streaming one n's K/V share L2.
// ---------------------------------------------------------------------------
__global__ __launch_bounds__(256) void attnO(const __hip_bfloat16* __restrict__ Q,
                                             const __hip_bfloat16* __restrict__ Kg,
                                             const __hip_bfloat16* __restrict__ Vt,
                                             const __hip_bfloat16* __restrict__ lf_pe,
                                             const __hip_bfloat16* __restrict__ Wo4,
                                             const float* __restrict__ bo,
                                             float* __restrict__ out) {
    __shared__ __align__(16) short al[16][264];
    int tid = threadIdx.x;
    int wave = tid >> 6, lane = tid & 63;
    int quad = lane >> 4, c16 = lane & 15;

    int id = blockIdx.x;
    int xcd = id & 7;
    int n = xcd & 3;                         // batch pinned to 2 XCDs
    int qt = (id >> 3) + ((xcd >> 2) << 5);  // 0..63
    int q0 = qt * 16;

    const f4v zf = {0.f, 0.f, 0.f, 0.f};
    // per-wave: heads h0=wave*2, h0+1
    const short* kbase[2];
    const short* v0base[2];
    const short* v1base[2];
    s8v aq[2];
#pragma unroll
    for (int hh = 0; hh < 2; ++hh) {
        int bh = n * NHEAD + wave * 2 + hh;
        const short* Qs = (const short*)Q + (size_t)bh * NPTS * DHD;
        aq[hh] = *(const s8v*)(Qs + (q0 + c16) * DHD + quad * 8);
        kbase[hh]  = (const short*)Kg + (size_t)bh * HWW * DHD + c16 * DHD + quad * 8;
        v0base[hh] = (const short*)Vt + (size_t)bh * DHD * VTROW + c16 * VTROW + quad * 8;
        v1base[hh] = v0base[hh] + 16 * VTROW;
    }

    f4v o[2][2];
    o[0][0] = zf; o[0][1] = zf; o[1][0] = zf; o[1][1] = zf;
    float lsum[2] = {0.f, 0.f};

    s8v kfA[2], kfB[2], vfA[2], vfB[2];
#pragma unroll
    for (int hh = 0; hh < 2; ++hh) {
        kfA[hh] = *(const s8v*)(kbase[hh]);
        kfB[hh] = *(const s8v*)(kbase[hh] + 16 * DHD);
        vfA[hh] = *(const s8v*)(v0base[hh]);
        vfB[hh] = *(const s8v*)(v1base[hh]);
    }

    for (int st = 0; st < HWW / 32; ++st) {
        bool more = (st + 1) < HWW / 32;
        s8v nkA[2], nkB[2], nvA[2], nvB[2];
        if (more) {
            int ko = (st + 1) * 32;
#pragma unroll
            for (int hh = 0; hh < 2; ++hh) {
                nkA[hh] = *(const s8v*)(kbase[hh] + ko * DHD);
                nkB[hh] = *(const s8v*)(kbase[hh] + ko * DHD + 16 * DHD);
                nvA[hh] = *(const s8v*)(v0base[hh] + ko);
                nvB[hh] = *(const s8v*)(v1base[hh] + ko);
            }
        }
#pragma unroll
        for (int hh = 0; hh < 2; ++hh) {
            f4v sA = MFMA_BF16(kfA[hh], aq[hh], zf, 0, 0, 0);   // keys 4q+r
            f4v sB = MFMA_BF16(kfB[hh], aq[hh], zf, 0, 0, 0);   // keys 16+4q+r
            float pA0 = __builtin_amdgcn_exp2f(sA[0]);
            float pA1 = __builtin_amdgcn_exp2f(sA[1]);
            float pA2 = __builtin_amdgcn_exp2f(sA[2]);
            float pA3 = __builtin_amdgcn_exp2f(sA[3]);
            float pB0 = __builtin_amdgcn_exp2f(sB[0]);
            float pB1 = __builtin_amdgcn_exp2f(sB[1]);
            float pB2 = __builtin_amdgcn_exp2f(sB[2]);
            float pB3 = __builtin_amdgcn_exp2f(sB[3]);
            lsum[hh] += ((pA0 + pA1) + (pA2 + pA3)) + ((pB0 + pB1) + (pB2 + pB3));
            union { u4v u; s8v s; } pf;
            pf.u = (u4v){packbf(pA1, pA0), packbf(pA3, pA2),
                         packbf(pB1, pB0), packbf(pB3, pB2)};
            o[hh][0] = MFMA_BF16(vfA[hh], pf.s, o[hh][0], 0, 0, 0);  // dh 0..15
            o[hh][1] = MFMA_BF16(vfB[hh], pf.s, o[hh][1], 0, 0, 0);  // dh 16..31
        }
        if (more) {
#pragma unroll
            for (int hh = 0; hh < 2; ++hh) {
                kfA[hh] = nkA[hh]; kfB[hh] = nkB[hh];
                vfA[hh] = nvA[hh]; vfB[hh] = nvB[hh];
            }
        }
    }

    // ---- stage lf_pe tile into AL (coalesced) ----
    {
        int rl = tid >> 4, sg = tid & 15;
        const short* srcp = (const short*)lf_pe + ((size_t)(n * NPTS + q0 + rl)) * DD + sg * 16;
        *(u4v*)&al[rl][sg * 16]     = *(const u4v*)(srcp);
        *(u4v*)&al[rl][sg * 16 + 8] = *(const u4v*)(srcp + 8);
    }
    __syncthreads();
    // ---- add normalized O into AL (each (q,col) owned by one lane) ----
#pragma unroll
    for (int hh = 0; hh < 2; ++hh) {
        float l = lsum[hh];
        l += __shfl_xor(l, 16);
        l += __shfl_xor(l, 32);
        float linv = 1.0f / l;
        int cb = (wave * 2 + hh) * 32;
#pragma unroll
        for (int half = 0; half < 2; ++half) {
#pragma unroll
            for (int r = 0; r < 4; ++r) {
                int col = cb + half * 16 + quad * 4 + r;
                __hip_bfloat16* slot = (__hip_bfloat16*)&al[c16][col];
                float v = __bfloat162float(*slot) + o[hh][half][r] * linv;
                *slot = __float2bfloat16(v);
            }
        }
    }
    __syncthreads();
    // ---- output GEMM: AL(16x256) @ Wo^T + bo -> fp32 out rows ----
    int m0 = n * NPTS + q0;
    int ch0 = wave * 64;
    f4v acc[4];
#pragma unroll
    for (int t = 0; t < 4; ++t) acc[t] = (f4v){0.f, 0.f, 0.f, 0.f};
#pragma unroll
    for (int ks = 0; ks < 8; ++ks) {
        s8v af = *(const s8v*)&al[c16][ks * 32 + quad * 8];
#pragma unroll
        for (int t = 0; t < 4; ++t) {
            const short* wp = (const short*)Wo4 + (ch0 + t * 16 + c16) * DD + ks * 32 + quad * 8;
            s8v bf = *(const s8v*)wp;
            acc[t] = MFMA_BF16(af, bf, acc[t], 0, 0, 0);
        }
    }
#pragma unroll
    for (int t = 0; t < 4; ++t) {
        int col = ch0 + t * 16 + c16;
        float bv = bo[col];
#pragma unroll
        for (int r = 0; r < 4; ++r) {
            int row = m0 + quad * 4 + r;
            out[(size_t)row * DD + col] = acc[t][r] + bv;
        }
    }
}

// ---------------------------------------------------------------------------
extern "C" void kernel_launch(void* const* d_in, const int* in_sizes, int n_in,
                              void* d_out, int out_size, void* d_ws, size_t ws_size,
                              hipStream_t stream) {
    const float* lf    = (const float*)d_in[0];
    const float* gfeat = (const float*)d_in[1];
    const float* Wq    = (const float*)d_in[2];
    const float* bq    = (const float*)d_in[3];
    const float* Wk    = (const float*)d_in[4];
    const float* bk    = (const float*)d_in[5];
    const float* Wv    = (const float*)d_in[6];
    const float* bv    = (const float*)d_in[7];
    const float* Wo    = (const float*)d_in[8];
    const float* bo    = (const float*)d_in[9];

    const size_t MB = 1u << 20;
    char* ws = (char*)d_ws;
    __hip_bfloat16* lf_pe_b = (__hip_bfloat16*)(ws);                          // 0..2 MB
    __hip_bfloat16* gf_pe_b = (__hip_bfloat16*)(ws + 2 * MB);                 // 2..10 MB
    __hip_bfloat16* W4      = (__hip_bfloat16*)(ws + 10 * MB);                // 10..10.5 MB
    __hip_bfloat16* Qb      = (__hip_bfloat16*)(ws + 10 * MB + 512 * 1024);   // 10.5..12.5
    __hip_bfloat16* Kb      = (__hip_bfloat16*)(ws + 12 * MB + 512 * 1024);   // 12.5..20.5
    __hip_bfloat16* Vtb     = (__hip_bfloat16*)(ws + 20 * MB + 512 * 1024);   // 20.5..29

    prep<<<dim3(5376), dim3(256), 0, stream>>>(lf, gfeat, Wq, Wk, Wv, Wo,
                                               lf_pe_b, gf_pe_b, W4);
    gemmQKV<<<dim3(1152), dim3(256), 0, stream>>>(lf_pe_b, gf_pe_b, W4, bq, bk, bv,
                                                  Qb, Kb, Vtb);
    attnO<<<dim3(256), dim3(256), 0, stream>>>(Qb, Kb, Vtb, lf_pe_b,
                                               W4 + 3 * DD * DD, bo, (float*)d_out);
}

// Round 13
// 158.738 us; speedup vs baseline: 1.2387x; 1.2387x over previous
//
#include <hip/hip_runtime.h>
#include <hip/hip_bf16.h>
#include <math.h>

// Problem constants
#define NB    4
#define NPTS  1024
#define DD    256
#define HWW   4096
#define NHEAD 8
#define DHD   32
#define VTROW 4128   // padded V^T row length in shorts (4096 + 32)

typedef short s8v  __attribute__((ext_vector_type(8)));   // 8 x bf16 bits
typedef float f4v  __attribute__((ext_vector_type(4)));
typedef float f4s  __attribute__((ext_vector_type(4)));
typedef unsigned int u2v __attribute__((ext_vector_type(2)));
typedef unsigned int u4v __attribute__((ext_vector_type(4)));

#define MFMA_BF16 __builtin_amdgcn_mfma_f32_16x16x32_bf16

// -log(10000)/256
#define PE_FACT (-9.210340371976184f / 256.0f)
// log2(e)/sqrt(32) -- folded into Q so S-MFMA output is the exp2 argument
#define QSCALE 0.2550348637f

// pack two fp32 into one dword of bf16s (truncation): lo16=bf16(lo), hi16=bf16(hi)
__device__ __forceinline__ unsigned packbf(float hi, float lo) {
    return __builtin_amdgcn_perm(__float_as_uint(hi), __float_as_uint(lo), 0x07060302u);
}
// RNE variant
__device__ __forceinline__ unsigned pack2rne(float lo, float hi) {
    __hip_bfloat16 a = __float2bfloat16(lo), b = __float2bfloat16(hi);
    return (unsigned)*(unsigned short*)&a | ((unsigned)*(unsigned short*)&b << 16);
}

// ---------------------------------------------------------------------------
// K1 (fused prep), vectorized:
//   blocks 0..1023    : lf_pe = local_feat + pos_enc(32x32) -> bf16 (4 elem/thr)
//   blocks 1024..5119 : gf_pe = transpose(global_feat) + pos_enc(64x64) (LDS)
//   blocks 5120..5375 : weights -> bf16 (Wq|Wk|Wv|Wo), 4 elem/thr
// ---------------------------------------------------------------------------
__global__ __launch_bounds__(256) void prep(const float* __restrict__ lf,
                                            const float* __restrict__ gfeat,
                                            const float* __restrict__ wq,
                                            const float* __restrict__ wk,
                                            const float* __restrict__ wv,
                                            const float* __restrict__ wo,
                                            __hip_bfloat16* __restrict__ lf_pe_b,
                                            __hip_bfloat16* __restrict__ gf_pe_b,
                                            __hip_bfloat16* __restrict__ W4) {
    __shared__ float tile[32][33];
    int b = blockIdx.x, tid = threadIdx.x;
    if (b < 1024) {
        int idx4 = (b * 256 + tid) * 4;            // < 4*1024*256, 4-aligned
        f4s f = *(const f4s*)(lf + idx4);
        int c = idx4 & 255;                        // even, 4 consecutive cols
        int p = (idx4 >> 8) & 1023;
        float x = (float)(p & 31) * (1.0f / 31.0f);
        float y = (float)(p >> 5) * (1.0f / 31.0f);
        float div0 = __expf((float)c * PE_FACT);
        float div2 = __expf((float)(c + 2) * PE_FACT);
        float e0 = f.x + __sinf(x * div0);
        float e1 = f.y + __cosf(y * div0);
        float e2 = f.z + __sinf(x * div2);
        float e3 = f.w + __cosf(y * div2);
        u2v o2 = { pack2rne(e0, e1), pack2rne(e2, e3) };
        *(u2v*)((unsigned*)lf_pe_b + (idx4 >> 1)) = o2;
    } else if (b < 5120) {
        int t = b - 1024;
        int n = t >> 10, r = t & 1023;
        int p0 = (r >> 3) * 32, c0 = (r & 7) * 32;
        int tx = tid & 31, ty = tid >> 5;           // 32 x 8, 4 rows each
#pragma unroll
        for (int i = 0; i < 4; ++i)
            tile[ty + 8 * i][tx] = gfeat[((size_t)n * DD + (c0 + ty + 8 * i)) * HWW + p0 + tx];
        __syncthreads();
#pragma unroll
        for (int i = 0; i < 4; ++i) {
            int p = p0 + ty + 8 * i, c = c0 + tx;
            float div = __expf((float)(c & ~1) * PE_FACT);
            float pe = (c & 1) ? __cosf((float)(p >> 6) * (1.0f / 63.0f) * div)
                               : __sinf((float)(p & 63) * (1.0f / 63.0f) * div);
            gf_pe_b[((size_t)n * HWW + p) * DD + c] = __float2bfloat16(tile[tx][ty + 8 * i] + pe);
        }
    } else {
        int idx4 = ((b - 5120) * 256 + tid) * 4;    // < 4*65536
        int m = idx4 >> 16, r = idx4 & 65535;
        const float* src = (m == 0) ? wq : (m == 1) ? wk : (m == 2) ? wv : wo;
        f4s f = *(const f4s*)(src + r);
        u2v o2 = { pack2rne(f.x, f.y), pack2rne(f.z, f.w) };
        *(u2v*)((unsigned*)W4 + (idx4 >> 1)) = o2;
    }
}

// ---------------------------------------------------------------------------
// K2: W-STATIONARY fused Q/K/V GEMM, pipelined over 2 m-tiles, all stores
//   LDS-bounced to coalesced 16B.
//   blocks 0..127    : Q  -> bf16 (n,h,NP,32)*QSCALE
//   blocks 128..1151 : K -> (n,h,HW,32); V -> (n,h,32,VTROW) sigma-transposed
// ---------------------------------------------------------------------------
__global__ __launch_bounds__(256, 2) void gemmQKV(const __hip_bfloat16* __restrict__ Aq,
                                                  const __hip_bfloat16* __restrict__ Akv,
                                                  const __hip_bfloat16* __restrict__ W4,
                                                  const float* __restrict__ bq,
                                                  const float* __restrict__ bk,
                                                  const float* __restrict__ bv,
                                                  __hip_bfloat16* __restrict__ Qb,
                                                  __hip_bfloat16* __restrict__ Kb,
                                                  __hip_bfloat16* __restrict__ Vtb) {
    __shared__ __align__(16) unsigned shbuf[2304];   // 9216 B, dual-purpose
    int tid = threadIdx.x;
    int wave = tid >> 6, lane = tid & 63;
    int quad = lane >> 4, c16 = lane & 15;
    int b = blockIdx.x;

    int typ, c0, mgrp, mstride;
    const short* Ap;
    const short* Wp;
    const float* bias;
    if (b < 128) {               // Q
        typ = 0; c0 = (b >> 5) * 64; mgrp = b & 31; mstride = 2048;
        Ap = (const short*)Aq; Wp = (const short*)W4; bias = bq;
    } else {                     // K or V
        int bb = b - 128;
        int combo = bb >> 7;     // 0..7
        mgrp = bb & 127; mstride = 8192;
        int mat = combo & 1;
        typ = 1 + mat;
        c0 = (combo >> 1) * 64;
        Ap = (const short*)Akv;
        Wp = (const short*)W4 + (1 + mat) * DD * DD;
        bias = mat ? bv : bk;
    }

    // ---- preload W fragments (32 x s8v) + bias ----
    s8v w[8][4];
    const short* wp0 = Wp + (c0 + c16) * DD + quad * 8;
#pragma unroll
    for (int ks = 0; ks < 8; ++ks)
#pragma unroll
        for (int t = 0; t < 4; ++t)
            w[ks][t] = *(const s8v*)(wp0 + t * 16 * DD + ks * 32);
    float bvv[4];
#pragma unroll
    for (int t = 0; t < 4; ++t) bvv[t] = bias[c0 + t * 16 + c16];

    // ---- both m-tiles' A fragments issued up front (pipelined) ----
    int mbase0 = mgrp * 64;
    int mbase1 = mbase0 + mstride;
    const short* ap0 = Ap + (mbase0 + wave * 16 + c16) * DD + quad * 8;
    const short* ap1 = Ap + (mbase1 + wave * 16 + c16) * DD + quad * 8;
    s8v a0[8], a1[8];
#pragma unroll
    for (int ks = 0; ks < 8; ++ks) a0[ks] = *(const s8v*)(ap0 + ks * 32);
#pragma unroll
    for (int ks = 0; ks < 8; ++ks) a1[ks] = *(const s8v*)(ap1 + ks * 32);

#pragma unroll
    for (int it = 0; it < 2; ++it) {
        int mbase = it ? mbase1 : mbase0;
        f4v acc[4];
#pragma unroll
        for (int t = 0; t < 4; ++t) acc[t] = (f4v){0.f, 0.f, 0.f, 0.f};
#pragma unroll
        for (int ks = 0; ks < 8; ++ks) {
            s8v a = it ? a1[ks] : a0[ks];
#pragma unroll
            for (int t = 0; t < 4; ++t)
                acc[t] = MFMA_BF16(a, w[ks][t], acc[t], 0, 0, 0);
        }

        if (typ != 2) {          // ---- Q / K: transpose bounce, coalesced store ----
            short* kt = (short*)shbuf;           // [64 rows][72 shorts]
            __syncthreads();     // prior iteration's readers done
#pragma unroll
            for (int t = 0; t < 4; ++t) {
#pragma unroll
                for (int r = 0; r < 4; ++r) {
                    float v = acc[t][r] + bvv[t];
                    if (typ == 0) v *= QSCALE;
                    __hip_bfloat16 hv = __float2bfloat16(v);
                    kt[(wave * 16 + quad * 4 + r) * 72 + t * 16 + c16] = *(short*)&hv;
                }
            }
            __syncthreads();
            int pl  = tid >> 2;          // local row 0..63
            int seg = tid & 3;           // 16-short (32B) segment
            const short* src = kt + pl * 72 + seg * 16;
            u4v w0 = *(const u4v*)(src);
            u4v w1 = *(const u4v*)(src + 8);
            int h   = (c0 >> 5) + (seg >> 1);
            int dh0 = (seg & 1) * 16;
            short* dst;
            if (typ == 0) {
                int row = mbase + pl;
                int n = row >> 10, p = row & 1023;
                dst = (short*)Qb + (((size_t)(n * NHEAD + h) << 10) + p) * DHD + dh0;
            } else {
                int n = mbase >> 12, p = (mbase & 4095) + pl;
                dst = (short*)Kb + (((size_t)(n * NHEAD + h) << 12) + p) * DHD + dh0;
            }
            *(u4v*)(dst)     = w0;
            *(u4v*)(dst + 8) = w1;
        } else {                 // ---- V: sigma-permuted transpose bounce ----
            unsigned (*stv)[36] = (unsigned (*)[36])shbuf;
            __syncthreads();     // protect stv from previous iteration's readers
#pragma unroll
            for (int t = 0; t < 4; ++t) {
#pragma unroll
                for (int rp = 0; rp < 2; ++rp) {
                    __hip_bfloat16 lo = __float2bfloat16(acc[t][2 * rp] + bvv[t]);
                    __hip_bfloat16 hi = __float2bfloat16(acc[t][2 * rp + 1] + bvv[t]);
                    unsigned dw = (unsigned)*(unsigned short*)&lo |
                                  ((unsigned)*(unsigned short*)&hi << 16);
                    stv[t * 16 + c16][wave * 8 + quad * 2 + rp] = dw;
                }
            }
            __syncthreads();
            int col = tid >> 2;              // 0..63
            int kd  = (tid & 3) * 8;         // out dword base (0,8,16,24)
            int grp = kd & 16;
            int ob  = kd & 15;
            unsigned vals[8];
#pragma unroll
            for (int i = 0; i < 8; ++i) {
                int o = ob + i;
                int idw = ((o >> 2) << 1) | (o & 1) | ((o & 2) << 2);  // inverse sigma
                vals[i] = stv[col][grp + idw];
            }
            int nblk = mbase >> 12;
            int kb   = mbase & 4095;
            int gh = (c0 + col) >> 5, gdh = (c0 + col) & 31;
            short* vp = (short*)Vtb + ((size_t)(nblk * NHEAD + gh) * DHD + gdh) * VTROW + kb + kd * 2;
            *(u4v*)(vp)     = (u4v){vals[0], vals[1], vals[2], vals[3]};
            *(u4v*)(vp + 8) = (u4v){vals[4], vals[5], vals[6], vals[7]};
        }
    }
}

// ---------------------------------------------------------------------------
// K3: attention partial. NO LDS, no cross-lane. 64 q-rows/wave.
//   S^T = K.Q^T -> exp2 -> in-lane pack (keys sigma-ordered) -> O^T = V^T.P^T.
//   grid: flat 128*NC, XCD-swizzled; writes bf16 O-partials + fp32 row-sums.
//   NOTE (R12): needs >=4 blocks/CU; fusing heads into one block (1 blk/CU)
//   exposed K/V L2 latency and cost +60 µs. Keep the split.
// ---------------------------------------------------------------------------
template <int NC>
__global__ __launch_bounds__(256) void attn(const __hip_bfloat16* __restrict__ Q,
                                            const __hip_bfloat16* __restrict__ Kg,
                                            const __hip_bfloat16* __restrict__ Vt,
                                            __hip_bfloat16* __restrict__ Opart,
                                            float* __restrict__ lpart) {
    constexpr int CK = HWW / NC;         // keys per chunk
    constexpr int NSTEP = CK / 32;

    int tid = threadIdx.x;
    int wave = tid >> 6, lane = tid & 63;
    int quad = lane >> 4, c16 = lane & 15;

    int id = blockIdx.x;
    int xcd = id & 7;
    int s = id >> 3;
    int qtile = s & 3;
    int gidx = ((s >> 2) << 3) | xcd;    // 0..32*NC-1
    int bh = gidx & 31;
    int chunk = gidx >> 5;

    int q0 = qtile * 256 + wave * 64;

    const short* Qs = (const short*)Q + (size_t)bh * NPTS * DHD;
    const short* Ks = (const short*)Kg + ((size_t)bh * HWW + (size_t)chunk * CK) * DHD;
    const short* Vs = (const short*)Vt + (size_t)bh * DHD * VTROW + (size_t)chunk * CK;

    s8v aq[4];
#pragma unroll
    for (int g = 0; g < 4; ++g)
        aq[g] = *(const s8v*)(Qs + (q0 + g * 16 + c16) * DHD + quad * 8);

    const f4v zf = {0.f, 0.f, 0.f, 0.f};
    f4v o[4][2];
#pragma unroll
    for (int g = 0; g < 4; ++g) { o[g][0] = zf; o[g][1] = zf; }
    float lsum[4] = {0.f, 0.f, 0.f, 0.f};

    const short* kbase  = Ks + c16 * DHD + quad * 8;
    const short* v0base = Vs + c16 * VTROW + quad * 8;
    const short* v1base = Vs + (16 + c16) * VTROW + quad * 8;

    s8v kfA = *(const s8v*)(kbase);
    s8v kfB = *(const s8v*)(kbase + 16 * DHD);
    s8v vfA = *(const s8v*)(v0base);
    s8v vfB = *(const s8v*)(v1base);

    for (int st = 0; st < NSTEP; ++st) {
        bool more = (st + 1) < NSTEP;
        s8v nkA, nkB, nvA, nvB;
        if (more) {
            int ko = (st + 1) * 32;
            nkA = *(const s8v*)(kbase + ko * DHD);
            nkB = *(const s8v*)(kbase + ko * DHD + 16 * DHD);
            nvA = *(const s8v*)(v0base + ko);
            nvB = *(const s8v*)(v1base + ko);
        }
#pragma unroll
        for (int g = 0; g < 4; ++g) {
            f4v sA = MFMA_BF16(kfA, aq[g], zf, 0, 0, 0);   // P^T keys 4q+r
            f4v sB = MFMA_BF16(kfB, aq[g], zf, 0, 0, 0);   // P^T keys 16+4q+r
            float pA0 = __builtin_amdgcn_exp2f(sA[0]);
            float pA1 = __builtin_amdgcn_exp2f(sA[1]);
            float pA2 = __builtin_amdgcn_exp2f(sA[2]);
            float pA3 = __builtin_amdgcn_exp2f(sA[3]);
            float pB0 = __builtin_amdgcn_exp2f(sB[0]);
            float pB1 = __builtin_amdgcn_exp2f(sB[1]);
            float pB2 = __builtin_amdgcn_exp2f(sB[2]);
            float pB3 = __builtin_amdgcn_exp2f(sB[3]);
            lsum[g] += ((pA0 + pA1) + (pA2 + pA3)) + ((pB0 + pB1) + (pB2 + pB3));
            // B-frag directly (V^T is sigma-ordered): k=8q+j <-> {sA r0..3, sB r0..3}
            union { u4v u; s8v s; } pf;
            pf.u = (u4v){packbf(pA1, pA0), packbf(pA3, pA2),
                         packbf(pB1, pB0), packbf(pB3, pB2)};
            o[g][0] = MFMA_BF16(vfA, pf.s, o[g][0], 0, 0, 0);  // dh 0..15
            o[g][1] = MFMA_BF16(vfB, pf.s, o[g][1], 0, 0, 0);  // dh 16..31
        }
        if (more) { kfA = nkA; kfB = nkB; vfA = nvA; vfB = nvB; }
    }

    // epilogue: O^T lane holds dh=16*half+4quad+r, q=q0+g*16+c16
    size_t obase = (size_t)(chunk * 32 + bh) * NPTS;
#pragma unroll
    for (int g = 0; g < 4; ++g) {
        float l = lsum[g];
        l += __shfl_xor(l, 16);
        l += __shfl_xor(l, 32);
        int q = q0 + g * 16 + c16;
        if (quad == 0) lpart[obase + q] = l;
        unsigned d0 = packbf(o[g][0][1], o[g][0][0]);
        unsigned d1 = packbf(o[g][0][3], o[g][0][2]);
        unsigned d2 = packbf(o[g][1][1], o[g][1][0]);
        unsigned d3 = packbf(o[g][1][3], o[g][1][2]);
        unsigned* op = (unsigned*)Opart + (obase + q) * (DHD / 2);
        *(u2v*)(op + 2 * quad)     = (u2v){d0, d1};
        *(u2v*)(op + 8 + 2 * quad) = (u2v){d2, d3};
    }
}

// ---------------------------------------------------------------------------
// K4 (fused): combine chunks into AL tile in LDS, then output GEMM.
//   grid 256 blocks x 16 rows (1 block/CU). AL = (sum O)/(sum l) + lf_pe;
//   out = AL @ Wo^T + bo (fp32).
// ---------------------------------------------------------------------------
template <int NC>
__global__ __launch_bounds__(256) void combineO(const __hip_bfloat16* __restrict__ Opart,
                                                const float* __restrict__ lpart,
                                                const __hip_bfloat16* __restrict__ lf_pe,
                                                const __hip_bfloat16* __restrict__ Wo4,
                                                const float* __restrict__ bo,
                                                float* __restrict__ out) {
    __shared__ __align__(16) short al[16][264];
    int tid = threadIdx.x;
    int m0 = blockIdx.x * 16;
    {   // phase 1: combine -> AL (bf16) in LDS. thread = (row, one 16-col seg)
        int rl  = tid >> 4;           // 0..15
        int seg = tid & 15;           // 16 cols each
        int h   = seg >> 1;
        int rg = m0 + rl;
        int n = rg >> 10, q = rg & 1023;
        size_t bhq = ((size_t)(n * NHEAD + h) << 10) + q;
        int dh0 = (seg & 1) * 16;     // offset within the head's 32 dh
        float l = 0.f;
        float ov[16];
#pragma unroll
        for (int d = 0; d < 16; ++d) ov[d] = 0.f;
#pragma unroll
        for (int ch = 0; ch < NC; ++ch) {
            size_t base = (size_t)ch * 32 * NPTS + bhq;
            l += lpart[base];
            const unsigned* op = (const unsigned*)((const short*)Opart + base * DHD + dh0);
#pragma unroll
            for (int dw = 0; dw < 8; ++dw) {
                unsigned u = op[dw];
                ov[2 * dw]     += __uint_as_float(u << 16);
                ov[2 * dw + 1] += __uint_as_float(u & 0xffff0000u);
            }
        }
        float linv = 1.0f / l;
        const unsigned* lp = (const unsigned*)((const short*)lf_pe + ((size_t)rg * DD + seg * 16));
        unsigned* dst = (unsigned*)&al[rl][seg * 16];
#pragma unroll
        for (int dw = 0; dw < 8; ++dw) {
            unsigned u = lp[dw];
            float x0 = ov[2 * dw] * linv     + __uint_as_float(u << 16);
            float x1 = ov[2 * dw + 1] * linv + __uint_as_float(u & 0xffff0000u);
            dst[dw] = packbf(x1, x0);
        }
    }
    __syncthreads();
    // phase 2: GEMM AL(16x256) @ Wo^T -> out rows m0..m0+15 (fp32)
    int wave = tid >> 6, lane = tid & 63;
    int quad = lane >> 4, c16 = lane & 15;
    int ch0 = wave * 64;
    f4v acc[4];
#pragma unroll
    for (int t = 0; t < 4; ++t) acc[t] = (f4v){0.f, 0.f, 0.f, 0.f};
#pragma unroll
    for (int ks = 0; ks < 8; ++ks) {
        s8v af = *(const s8v*)&al[c16][ks * 32 + quad * 8];
#pragma unroll
        for (int t = 0; t < 4; ++t) {
            const short* wp = (const short*)Wo4 + (ch0 + t * 16 + c16) * DD + ks * 32 + quad * 8;
            s8v bf = *(const s8v*)wp;
            acc[t] = MFMA_BF16(af, bf, acc[t], 0, 0, 0);
        }
    }
#pragma unroll
    for (int t = 0; t < 4; ++t) {
        int col = ch0 + t * 16 + c16;
        float bv = bo[col];
#pragma unroll
        for (int r = 0; r < 4; ++r) {
            int row = m0 + quad * 4 + r;
            out[(size_t)row * DD + col] = acc[t][r] + bv;
        }
    }
}

// ---------------------------------------------------------------------------
extern "C" void kernel_launch(void* const* d_in, const int* in_sizes, int n_in,
                              void* d_out, int out_size, void* d_ws, size_t ws_size,
                              hipStream_t stream) {
    const float* lf    = (const float*)d_in[0];
    const float* gfeat = (const float*)d_in[1];
    const float* Wq    = (const float*)d_in[2];
    const float* bq    = (const float*)d_in[3];
    const float* Wk    = (const float*)d_in[4];
    const float* bk    = (const float*)d_in[5];
    const float* Wv    = (const float*)d_in[6];
    const float* bv    = (const float*)d_in[7];
    const float* Wo    = (const float*)d_in[8];
    const float* bo    = (const float*)d_in[9];

    const size_t MB = 1u << 20;
    char* ws = (char*)d_ws;
    __hip_bfloat16* lf_pe_b = (__hip_bfloat16*)(ws);                          // 0..2 MB
    __hip_bfloat16* gf_pe_b = (__hip_bfloat16*)(ws + 2 * MB);                 // 2..10 MB
    __hip_bfloat16* W4      = (__hip_bfloat16*)(ws + 10 * MB);                // 10..10.5 MB
    __hip_bfloat16* Qb      = (__hip_bfloat16*)(ws + 10 * MB + 512 * 1024);   // 10.5..12.5
    __hip_bfloat16* Kb      = (__hip_bfloat16*)(ws + 12 * MB + 512 * 1024);   // 12.5..20.5
    __hip_bfloat16* Vtb     = (__hip_bfloat16*)(ws + 20 * MB + 512 * 1024);   // 20.5..29
    float*          lpart   = (float*)(ws + 31 * MB);                         // 31..32 MB
    __hip_bfloat16* Opart   = (__hip_bfloat16*)(ws + 32 * MB);                // 32..32+NC*2 MB

    prep<<<dim3(5376), dim3(256), 0, stream>>>(lf, gfeat, Wq, Wk, Wv, Wo,
                                               lf_pe_b, gf_pe_b, W4);
    gemmQKV<<<dim3(1152), dim3(256), 0, stream>>>(lf_pe_b, gf_pe_b, W4, bq, bk, bv,
                                                  Qb, Kb, Vtb);

    if (ws_size >= 48 * MB) {
        attn<8><<<dim3(128 * 8), dim3(256), 0, stream>>>(Qb, Kb, Vtb, Opart, lpart);
        combineO<8><<<dim3(256), dim3(256), 0, stream>>>(Opart, lpart, lf_pe_b,
                                                         W4 + 3 * DD * DD, bo, (float*)d_out);
    } else if (ws_size >= 40 * MB) {
        attn<4><<<dim3(128 * 4), dim3(256), 0, stream>>>(Qb, Kb, Vtb, Opart, lpart);
        combineO<4><<<dim3(256), dim3(256), 0, stream>>>(Opart, lpart, lf_pe_b,
                                                         W4 + 3 * DD * DD, bo, (float*)d_out);
    } else if (ws_size >= 36 * MB) {
        attn<2><<<dim3(128 * 2), dim3(256), 0, stream>>>(Qb, Kb, Vtb, Opart, lpart);
        combineO<2><<<dim3(256), dim3(256), 0, stream>>>(Opart, lpart, lf_pe_b,
                                                         W4 + 3 * DD * DD, bo, (float*)d_out);
    } else {
        attn<1><<<dim3(128 * 1), dim3(256), 0, stream>>>(Qb, Kb, Vtb, Opart, lpart);
        combineO<1><<<dim3(256), dim3(256), 0, stream>>>(Opart, lpart, lf_pe_b,
                                                         W4 + 3 * DD * DD, bo, (float*)d_out);
    }
}